// Round 17
// baseline (582.611 us; speedup 1.0000x reference)
//
#include <hip/hip_runtime.h>
#include <hip/hip_bf16.h>

// MoE layer: B=2,S=2048,D=1024,F=4096,E=8,K=2. T=4096 tokens.
// R17: R16 + (a) assign folded into fused0 via last-block ticket
// (device-scope fences), (b) GEMM2 ksplit=8 top tier. Core GEMM unchanged
// (R11 128x128 BK=64, 2-buffer, static XCD swizzle).

#define T_TOK 4096
#define D_DIM 1024
#define F_DIM 4096
#define E_NUM 8
#define CAP_ROWS 9216          // 8192 + 8*128 padding headroom
#define N_TILES (CAP_ROWS/128) // 72

typedef __attribute__((ext_vector_type(8))) short short8v;
typedef __attribute__((ext_vector_type(8))) unsigned short ushort8v;
typedef __attribute__((ext_vector_type(4))) float f32x4;

static __device__ __forceinline__ unsigned short f2bf(float f){
  union { float f; unsigned u; } v; v.f = f;
  unsigned r = (v.u + 0x7fffu + ((v.u >> 16) & 1u)) >> 16;  // RNE
  return (unsigned short)r;
}
static __device__ __forceinline__ float bf2f(unsigned short s){
  union { unsigned u; float f; } v; v.u = ((unsigned)s) << 16;
  return v.f;
}

static __device__ __forceinline__ void gload16(const void* g, void* l) {
  __builtin_amdgcn_global_load_lds(
      (const __attribute__((address_space(1))) unsigned int*)g,
      (__attribute__((address_space(3))) unsigned int*)l, 16, 0, 0);
}

// fused0: blocks [0,1024) = router; last-finishing router block also does
// scan + tile_e + assign (ticket). blocks [1024,2048) = W1 transpose strips.
__global__ __launch_bounds__(256) void k_fused0(
    const float* __restrict__ x, const float* __restrict__ Wr,
    const float* __restrict__ br, float* __restrict__ probs_out,
    int* __restrict__ topi, float* __restrict__ topw, int* __restrict__ counts,
    unsigned short* __restrict__ xbf,
    const float* __restrict__ W1, unsigned short* __restrict__ W1t,
    int* __restrict__ done, int* __restrict__ cursor,
    int* __restrict__ rows_token, float* __restrict__ rows_w,
    int* __restrict__ pair_of, int* __restrict__ tile_e)
{
  __shared__ unsigned short ls[64][66];
  const int b = blockIdx.x;
  if (b < T_TOK/4) {
    const int lane = threadIdx.x & 63;
    const int t = b * 4 + (threadIdx.x >> 6);
    float xv[16];
    #pragma unroll
    for (int i = 0; i < 16; ++i) xv[i] = x[(size_t)t*D_DIM + i*64 + lane];
    #pragma unroll
    for (int i = 0; i < 16; ++i) xbf[(size_t)t*D_DIM + i*64 + lane] = f2bf(xv[i]);
    float pe[E_NUM];
    #pragma unroll
    for (int e = 0; e < E_NUM; ++e) {
      float p = 0.f;
      #pragma unroll
      for (int i = 0; i < 16; ++i) p += xv[i] * Wr[(i*64 + lane)*E_NUM + e];
      #pragma unroll
      for (int off = 32; off >= 1; off >>= 1) p += __shfl_xor(p, off);
      pe[e] = p + br[e];
    }
    float m = pe[0];
    #pragma unroll
    for (int e = 1; e < E_NUM; ++e) m = fmaxf(m, pe[e]);
    float s = 0.f;
    #pragma unroll
    for (int e = 0; e < E_NUM; ++e) { pe[e] = expf(pe[e] - m); s += pe[e]; }
    const float inv = 1.f / s;
    int e1 = 0; float v1 = pe[0];
    #pragma unroll
    for (int e = 1; e < E_NUM; ++e) if (pe[e] > v1) { v1 = pe[e]; e1 = e; }
    int e2 = (e1 == 0) ? 1 : 0; float v2 = pe[e2];
    #pragma unroll
    for (int e = 0; e < E_NUM; ++e) if (e != e1 && pe[e] > v2) { v2 = pe[e]; e2 = e; }
    if (lane == 0) {
      #pragma unroll
      for (int e = 0; e < E_NUM; ++e) probs_out[(size_t)t*E_NUM + e] = pe[e] * inv;
      topi[t*2+0] = e1; topw[t*2+0] = v1 * inv;
      topi[t*2+1] = e2; topw[t*2+1] = v2 * inv;
      atomicAdd(&counts[e1], 1);
      atomicAdd(&counts[e2], 1);
    }
    // ---- ticket: last router block performs scan + assign ----
    __syncthreads();
    __threadfence();                       // publish topi/topw/counts
    __syncthreads();
    __shared__ int ticket_s;
    if (threadIdx.x == 0) ticket_s = atomicAdd(done, 1);
    __syncthreads();
    if (ticket_s == T_TOK/4 - 1) {
      __threadfence();                     // acquire: see all blocks' stores
      __shared__ int base_s[E_NUM + 1];
      if (threadIdx.x == 0) {
        int base = 0;
        #pragma unroll
        for (int e = 0; e < E_NUM; ++e) {
          base_s[e] = base;
          base += ((counts[e] + 127) >> 7) << 7;
        }
        base_s[E_NUM] = base;
      }
      __syncthreads();
      if (threadIdx.x < N_TILES) {
        const int r0 = threadIdx.x << 7;
        int e = -1;
        #pragma unroll
        for (int k = 0; k < E_NUM; ++k)
          if (r0 >= base_s[k] && r0 < base_s[k+1]) e = k;
        tile_e[threadIdx.x] = e;
      }
      for (int tt = threadIdx.x; tt < T_TOK; tt += 256) {
        #pragma unroll
        for (int k = 0; k < 2; ++k) {
          const int e = topi[tt*2+k];
          const int slot = atomicAdd(&cursor[e], 1);
          const int pid = base_s[e] + slot;
          rows_token[pid] = tt;
          rows_w[pid] = topw[tt*2+k];
          pair_of[tt*2+k] = pid;
        }
      }
    }
  } else {
    // W1 [E][D][F] fp32 -> W1t [E][F][D] bf16; strip = 8 subtiles of 64x64
    const int tb = b - T_TOK/4;               // 0..1023
    const int e = tb >> 7;
    const int rem = tb & 127;
    const int c0 = (rem >> 1) * 64;           // 64 c-tiles over F
    const int rg = (rem & 1) * 512;           // 2 r-groups over D
    const size_t eo = (size_t)e * D_DIM * F_DIM;
    const int t = threadIdx.x;
    const int rr = t >> 4, cc = (t & 15) * 4;
    const int kc = (t & 7) * 8, nn0 = t >> 3;
    for (int s = 0; s < 8; ++s) {
      const int r0 = rg + s * 64;
      #pragma unroll
      for (int p = 0; p < 4; ++p) {
        const float4 v = *(const float4*)&W1[eo + (size_t)(r0 + p*16 + rr)*F_DIM + c0 + cc];
        ls[p*16+rr][cc+0]=f2bf(v.x); ls[p*16+rr][cc+1]=f2bf(v.y);
        ls[p*16+rr][cc+2]=f2bf(v.z); ls[p*16+rr][cc+3]=f2bf(v.w);
      }
      __syncthreads();
      #pragma unroll
      for (int p = 0; p < 2; ++p) {
        const int nn = nn0 + p*32;
        ushort8v o;
        #pragma unroll
        for (int j = 0; j < 8; ++j) o[j] = ls[kc + j][nn];
        *(ushort8v*)&W1t[eo + (size_t)(c0 + nn)*D_DIM + r0 + kc] = o;
      }
      __syncthreads();
    }
  }
}

// transpose + convert (fallback path): per expert, fp32 [R][C] -> bf16 [C][R]
template<int R, int C>
__global__ __launch_bounds__(256) void k_tcvt(const float* __restrict__ in,
                                              unsigned short* __restrict__ out)
{
  const size_t eo = (size_t)blockIdx.z * R * C;
  const int r0 = blockIdx.y * 64, c0 = blockIdx.x * 64;
  __shared__ unsigned short ls[64][66];
  const int t = threadIdx.x;
  const int rr = t >> 4, cc = (t & 15) * 4;
  #pragma unroll
  for (int p = 0; p < 4; ++p) {
    const float4 v = *(const float4*)&in[eo + (size_t)(r0 + p*16 + rr)*C + c0 + cc];
    ls[p*16+rr][cc+0]=f2bf(v.x); ls[p*16+rr][cc+1]=f2bf(v.y);
    ls[p*16+rr][cc+2]=f2bf(v.z); ls[p*16+rr][cc+3]=f2bf(v.w);
  }
  __syncthreads();
  const int kc = (t & 7) * 8, nn0 = t >> 3;
  #pragma unroll
  for (int p = 0; p < 2; ++p) {
    const int nn = nn0 + p*32;
    ushort8v o;
    #pragma unroll
    for (int j = 0; j < 8; ++j) o[j] = ls[kc + j][nn];
    *(ushort8v*)&out[eo + (size_t)(c0 + nn)*R + r0 + kc] = o;
  }
}

// R11 GEMM tile body: BM=BN=128, BK=64, 4 waves (2Mx2N), 2-buffer 64KB LDS.
// Per K-tile: stage(t+1)->buf^1, 16 ds_read, 32 MFMA (setprio), vmcnt(0), bar.
// EPI 1: relu(acc+bias) -> h.   EPI 2: (acc + (z==0)*bias)*rows_w -> ypart[z].
template<bool GATHER, int NDIM, int KFULL, int EPI>
static __device__ __forceinline__ void gemm_tile(
    const unsigned short* __restrict__ A,
    const unsigned short* __restrict__ Bt,
    const float* __restrict__ bias,
    const int* __restrict__ tile_e,
    const int* __restrict__ rows_token,
    const float* __restrict__ rows_w,
    unsigned short* __restrict__ outp,
    int bx, int by, int z, int nkt, int kch,
    unsigned short (*LB)[256*64])
{
  const int e = tile_e[by];
  if (e < 0) return;
  const int rt = by * 128;
  const int ntc = bx * 128;
  const int koff = z * kch;
  const int tid = threadIdx.x;
  const int lane = tid & 63;
  const int w = tid >> 6;
  const int lr = lane >> 3;
  const int g  = (lane & 7) ^ lr;          // pre-swizzled 16B chunk
  const unsigned short* gp[8];
  unsigned lbase[8];
  if (w < 2) {
    #pragma unroll
    for (int i = 0; i < 8; ++i) {
      const int rl = w*64 + i*8 + lr;
      const int rowidx = GATHER ? rows_token[rt + rl] : (rt + rl);
      gp[i] = A + (size_t)rowidx * KFULL + koff + g*8;
      lbase[i] = (unsigned)((w*64 + i*8) * 64);
    }
  } else {
    const unsigned short* Be = Bt + (size_t)e * NDIM * KFULL;
    #pragma unroll
    for (int i = 0; i < 8; ++i) {
      const int rl = (w-2)*64 + i*8 + lr;
      gp[i] = Be + (size_t)(ntc + rl) * KFULL + koff + g*8;
      lbase[i] = (unsigned)((128*64) + ((w-2)*64 + i*8) * 64);
    }
  }
  const int wr = w >> 1, wc = w & 1;       // 2M x 2N, wave tile 64x64
  const int cl = lane & 15, rgb = lane >> 4;
  const int sz = cl & 7;                   // read-side XOR (row&7 == cl&7)
  f32x4 acc[4][4] = {};

  #define STG8(tt, bb)                                          \
    { const int _ko = (tt) * 64;                                \
      _Pragma("unroll")                                         \
      for (int _i = 0; _i < 8; ++_i)                            \
        gload16(gp[_i] + _ko, &LB[bb][lbase[_i]]); }

  STG8(0, 0)
  asm volatile("s_waitcnt vmcnt(0)" ::: "memory");
  __builtin_amdgcn_s_barrier();

  for (int t = 0; t < nkt; ++t) {
    const int bb = t & 1;
    if (t + 1 < nkt) STG8(t+1, bb^1)       // flies under reads+MFMA
    const unsigned short* Sb = &LB[bb][0];
    short8v a[4][2], b[4][2];
    #pragma unroll
    for (int m = 0; m < 4; ++m) {
      a[m][0] = *(const short8v*)&Sb[(wr*64 + m*16 + cl)*64 + ((0*4+rgb)^sz)*8];
      a[m][1] = *(const short8v*)&Sb[(wr*64 + m*16 + cl)*64 + ((1*4+rgb)^sz)*8];
    }
    #pragma unroll
    for (int n = 0; n < 4; ++n) {
      b[n][0] = *(const short8v*)&Sb[(128*64) + (wc*64 + n*16 + cl)*64 + ((0*4+rgb)^sz)*8];
      b[n][1] = *(const short8v*)&Sb[(128*64) + (wc*64 + n*16 + cl)*64 + ((1*4+rgb)^sz)*8];
    }
    __builtin_amdgcn_s_setprio(1);
    #pragma unroll
    for (int m = 0; m < 4; ++m)
      #pragma unroll
      for (int n = 0; n < 4; ++n) {
        acc[m][n] = __builtin_amdgcn_mfma_f32_16x16x32_bf16(a[m][0], b[n][0], acc[m][n], 0, 0, 0);
        acc[m][n] = __builtin_amdgcn_mfma_f32_16x16x32_bf16(a[m][1], b[n][1], acc[m][n], 0, 0, 0);
      }
    __builtin_amdgcn_s_setprio(0);
    asm volatile("s_waitcnt vmcnt(0)" ::: "memory");   // t+1 landed
    __builtin_amdgcn_s_barrier();
  }
  #undef STG8

  // epilogue: C/D layout col = lane&15, row = (lane>>4)*4 + reg  [m89]
  unsigned short* op = outp;
  if (EPI == 2) op += (size_t)z * CAP_ROWS * NDIM;
  const bool addb = (EPI == 1) || (z == 0);
  const size_t ebias = (size_t)e * NDIM;
  #pragma unroll
  for (int m = 0; m < 4; ++m) {
    const int row = rt + wr*64 + m*16 + rgb*4;
    float4 rw4 = make_float4(0,0,0,0);
    if (EPI == 2) rw4 = *(const float4*)&rows_w[row];
    #pragma unroll
    for (int n = 0; n < 4; ++n) {
      const int col = ntc + wc*64 + n*16 + cl;
      const float bv = addb ? bias[ebias + col] : 0.f;
      #pragma unroll
      for (int r = 0; r < 4; ++r) {
        float v = acc[m][n][r] + bv;
        if (EPI == 1) v = fmaxf(v, 0.f);
        else          v *= ((const float*)&rw4)[r];
        const unsigned short hb = f2bf(v);
        const unsigned short ob = (unsigned short)__shfl_xor((int)(unsigned)hb, 1);
        if ((lane & 1) == 0) {
          const unsigned pk = (unsigned)hb | ((unsigned)ob << 16);
          *(unsigned*)&op[(size_t)(row + r)*NDIM + col] = pk;
        }
      }
    }
  }
}

// standalone GEMM with R11's XCD-bijective B-panel-major swizzle
template<bool GATHER, int NDIM, int KFULL, int EPI>
__global__ __launch_bounds__(256, 2) void k_gemm(
    const unsigned short* __restrict__ A,
    const unsigned short* __restrict__ Bt,
    const float* __restrict__ bias,
    const int* __restrict__ tile_e,
    const int* __restrict__ rows_token,
    const float* __restrict__ rows_w,
    unsigned short* __restrict__ outp,
    int nkt, int kch)
{
  __shared__ __align__(16) unsigned short LB[2][256 * 64];
  const int tot = gridDim.x * gridDim.y;
  int flat = blockIdx.x * gridDim.y + blockIdx.y;
  flat = (flat & 7) * (tot >> 3) + (flat >> 3);
  gemm_tile<GATHER, NDIM, KFULL, EPI>(A, Bt, bias, tile_e, rows_token, rows_w,
                                      outp, flat / gridDim.y, flat % gridDim.y,
                                      blockIdx.z, nkt, kch, LB);
}

// fused launch: blocks [0,2304) = GEMM1 tiles (R11 mapping);
// blocks [2304, 2304+1024) = W2 transpose strips (8x 64x64 subtiles each).
__global__ __launch_bounds__(256, 2) void k_fused1(
    const unsigned short* __restrict__ xbf,
    const unsigned short* __restrict__ W1t,
    const float* __restrict__ b1,
    const int* __restrict__ tile_e,
    const int* __restrict__ rows_token,
    const float* __restrict__ rows_w,
    unsigned short* __restrict__ h,
    const float* __restrict__ W2,
    unsigned short* __restrict__ W2t)
{
  __shared__ __align__(16) unsigned short LB[2][256 * 64];
  constexpr int NG = (F_DIM/128) * N_TILES;   // 2304
  const int b = blockIdx.x;
  if (b < NG) {
    const int x = b & 31;                     // F_DIM/128 = 32
    const int y = b >> 5;
    int flat = x * N_TILES + y;
    flat = (flat & 7) * (NG >> 3) + (flat >> 3);
    gemm_tile<true, F_DIM, D_DIM, 1>(xbf, W1t, b1, tile_e, rows_token, rows_w,
                                     h, flat / N_TILES, flat % N_TILES, 0,
                                     D_DIM/64, D_DIM, LB);
  } else {
    // W2 [E][F][D] fp32 -> W2t [E][D][F] bf16; strip = 8 r-subtiles
    auto ls = (unsigned short (*)[66])(&LB[0][0]);
    const int tb = b - NG;                    // 0..1023
    const int e = tb >> 7;
    const int rem = tb & 127;
    const int c0 = (rem & 15) * 64;
    const int rg = (rem >> 4) * 512;
    const size_t eo = (size_t)e * F_DIM * D_DIM;
    const int t = threadIdx.x;
    const int rr = t >> 4, cc = (t & 15) * 4;
    const int kc = (t & 7) * 8, nn0 = t >> 3;
    for (int s = 0; s < 8; ++s) {
      const int r0 = rg + s * 64;
      #pragma unroll
      for (int p = 0; p < 4; ++p) {
        const float4 v = *(const float4*)&W2[eo + (size_t)(r0 + p*16 + rr)*D_DIM + c0 + cc];
        ls[p*16+rr][cc+0]=f2bf(v.x); ls[p*16+rr][cc+1]=f2bf(v.y);
        ls[p*16+rr][cc+2]=f2bf(v.z); ls[p*16+rr][cc+3]=f2bf(v.w);
      }
      __syncthreads();
      #pragma unroll
      for (int p = 0; p < 2; ++p) {
        const int nn = nn0 + p*32;
        ushort8v o;
        #pragma unroll
        for (int j = 0; j < 8; ++j) o[j] = ls[kc + j][nn];
        *(ushort8v*)&W2t[eo + (size_t)(c0 + nn)*F_DIM + r0 + kc] = o;
      }
      __syncthreads();
    }
  }
}

// out[t] = sum_k sum_s ypart[s][pair_k(t)]  (fixed order -> deterministic)
__global__ __launch_bounds__(256) void k_combine(
    const unsigned short* __restrict__ yp, const int* __restrict__ pair_of,
    float* __restrict__ out, int ksplit)
{
  const int gid = blockIdx.x * 256 + threadIdx.x;   // T*D/8 threads
  const int t = gid >> 7;
  const int c = (gid & 127) * 8;
  float o[8] = {0,0,0,0,0,0,0,0};
  #pragma unroll
  for (int k = 0; k < 2; ++k) {
    const int p = pair_of[t*2+k];
    for (int s = 0; s < ksplit; ++s) {
      const ushort8v v = *(const ushort8v*)&yp[((size_t)s*CAP_ROWS + p)*D_DIM + c];
      #pragma unroll
      for (int j = 0; j < 8; ++j) o[j] += bf2f(v[j]);
    }
  }
  float4 o0; o0.x=o[0]; o0.y=o[1]; o0.z=o[2]; o0.w=o[3];
  float4 o1; o1.x=o[4]; o1.y=o[5]; o1.z=o[6]; o1.w=o[7];
  *(float4*)&out[(size_t)t*D_DIM + c]     = o0;
  *(float4*)&out[(size_t)t*D_DIM + c + 4] = o1;
}

extern "C" void kernel_launch(void* const* d_in, const int* in_sizes, int n_in,
                              void* d_out, int out_size, void* d_ws, size_t ws_size,
                              hipStream_t stream)
{
  const float* x  = (const float*)d_in[0];
  const float* Wr = (const float*)d_in[1];
  const float* br = (const float*)d_in[2];
  const float* W1 = (const float*)d_in[3];
  const float* b1 = (const float*)d_in[4];
  const float* W2 = (const float*)d_in[5];
  const float* b2 = (const float*)d_in[6];
  (void)in_sizes; (void)n_in; (void)out_size;

  float* out   = (float*)d_out;
  float* probs = out + (size_t)T_TOK * D_DIM;

  char* w = (char*)d_ws;
  size_t off = 0;
  // contiguous zero-init region
  int*   counts     = (int*)(w + off); off += 256;
  int*   cursor     = (int*)(w + off); off += 256;
  int*   done       = (int*)(w + off); off += 256;
  int*   rows_token = (int*)(w + off); off += (size_t)CAP_ROWS*4;
  float* rows_w     = (float*)(w + off); off += (size_t)CAP_ROWS*4;
  const size_t zbytes = off;
  int*   tile_e     = (int*)(w + off); off += 3072;
  int*   topi       = (int*)(w + off); off += (size_t)T_TOK*2*4;
  float* topw       = (float*)(w + off); off += (size_t)T_TOK*2*4;
  int*   pair_of    = (int*)(w + off); off += (size_t)T_TOK*2*4;
  off = (off + 255) & ~(size_t)255;
  unsigned short* xbf = (unsigned short*)(w + off); off += (size_t)T_TOK*D_DIM*2;
  unsigned short* W1t = (unsigned short*)(w + off); off += (size_t)E_NUM*D_DIM*F_DIM*2;

  const size_t WT = (size_t)E_NUM*D_DIM*F_DIM*2;   // 67.1 MB
  const size_t HB = (size_t)CAP_ROWS*F_DIM*2;      // 75.5 MB
  const size_t YP = (size_t)CAP_ROWS*D_DIM*2;      // 18.9 MB

  // decision tree (deterministic: ws_size fixed per run)
  bool fused; int ksplit;
  if      (ws_size >= off + WT + HB + 8*YP) { fused = true;  ksplit = 8; }
  else if (ws_size >= off + WT + HB + 4*YP) { fused = true;  ksplit = 4; }
  else if (ws_size >= off + WT + HB + 2*YP) { fused = true;  ksplit = 2; }
  else if (ws_size >= off + HB + 4*YP)      { fused = false; ksplit = 4; }
  else if (ws_size >= off + HB + 2*YP)      { fused = false; ksplit = 2; }
  else                                      { fused = false; ksplit = 1; }

  unsigned short* W2t;
  unsigned short* h;
  if (fused) {
    W2t = (unsigned short*)(w + off); off += WT;
    h   = (unsigned short*)(w + off); off += HB;
  } else {
    W2t = W1t;                                   // sequential reuse
    h   = (unsigned short*)(w + off); off += HB;
  }
  unsigned short* yp = (unsigned short*)(w + off);
  const int kch2 = F_DIM / ksplit;
  const int nkt2 = kch2 / 64;

  hipMemsetAsync(d_ws, 0, zbytes, stream);
  // fused0: router (1024 blocks, last one does scan+assign) + W1t (1024 strips)
  k_fused0<<<T_TOK/4 + 1024, 256, 0, stream>>>(
      x, Wr, br, probs, topi, topw, counts, xbf, W1, W1t,
      done, cursor, rows_token, rows_w, pair_of, tile_e);
  if (fused) {
    // GEMM1 (2304 tiles) + W2 transpose (1024 strips) in ONE launch
    k_fused1<<<(F_DIM/128)*N_TILES + 1024, 256, 0, stream>>>(
        xbf, W1t, b1, tile_e, rows_token, rows_w, h, W2, W2t);
  } else {
    k_gemm<true, F_DIM, D_DIM, 1><<<dim3(F_DIM/128, N_TILES), 256, 0, stream>>>(
        xbf, W1t, b1, tile_e, rows_token, rows_w, h, D_DIM/64, D_DIM);
    k_tcvt<F_DIM, D_DIM><<<dim3(D_DIM/64, F_DIM/64, E_NUM), 256, 0, stream>>>(W2, W2t);
  }
  // GEMM2: K split into ksplit chunks along blockIdx.z
  k_gemm<false, D_DIM, F_DIM, 2><<<dim3(D_DIM/128, N_TILES, ksplit), 256, 0, stream>>>(
      h, W2t, b2, tile_e, rows_token, rows_w, yp, nkt2, kch2);
  k_combine<<<T_TOK * D_DIM / 8 / 256, 256, 0, stream>>>(yp, pair_of, out, ksplit);
}

// Round 18
// 439.121 us; speedup vs baseline: 1.3268x; 1.3268x over previous
//
#include <hip/hip_runtime.h>
#include <hip/hip_bf16.h>

// MoE layer: B=2,S=2048,D=1024,F=4096,E=8,K=2. T=4096 tokens.
// R18: revert to R16 (measured best, 440us). R17's ticket-fold caused a
// device-fence serialization in fused0 (45->280us) — removed. Structure:
// fused0(router+W1t) -> assign -> fused1(GEMM1+W2t) -> gemm2(ksplit) -> combine.

#define T_TOK 4096
#define D_DIM 1024
#define F_DIM 4096
#define E_NUM 8
#define CAP_ROWS 9216          // 8192 + 8*128 padding headroom
#define N_TILES (CAP_ROWS/128) // 72

typedef __attribute__((ext_vector_type(8))) short short8v;
typedef __attribute__((ext_vector_type(8))) unsigned short ushort8v;
typedef __attribute__((ext_vector_type(4))) float f32x4;

static __device__ __forceinline__ unsigned short f2bf(float f){
  union { float f; unsigned u; } v; v.f = f;
  unsigned r = (v.u + 0x7fffu + ((v.u >> 16) & 1u)) >> 16;  // RNE
  return (unsigned short)r;
}
static __device__ __forceinline__ float bf2f(unsigned short s){
  union { unsigned u; float f; } v; v.u = ((unsigned)s) << 16;
  return v.f;
}

static __device__ __forceinline__ void gload16(const void* g, void* l) {
  __builtin_amdgcn_global_load_lds(
      (const __attribute__((address_space(1))) unsigned int*)g,
      (__attribute__((address_space(3))) unsigned int*)l, 16, 0, 0);
}

// fused0: blocks [0,1024) = router (one wave per token; probs+top2+xbf);
// blocks [1024,2048) = W1 [E][D][F] fp32 -> W1t [E][F][D] bf16 strips.
__global__ __launch_bounds__(256) void k_fused0(
    const float* __restrict__ x, const float* __restrict__ Wr,
    const float* __restrict__ br, float* __restrict__ probs_out,
    int* __restrict__ topi, float* __restrict__ topw, int* __restrict__ counts,
    unsigned short* __restrict__ xbf,
    const float* __restrict__ W1, unsigned short* __restrict__ W1t)
{
  __shared__ unsigned short ls[64][66];
  const int b = blockIdx.x;
  if (b < T_TOK/4) {
    const int lane = threadIdx.x & 63;
    const int t = b * 4 + (threadIdx.x >> 6);
    float xv[16];
    #pragma unroll
    for (int i = 0; i < 16; ++i) xv[i] = x[(size_t)t*D_DIM + i*64 + lane];
    #pragma unroll
    for (int i = 0; i < 16; ++i) xbf[(size_t)t*D_DIM + i*64 + lane] = f2bf(xv[i]);
    float pe[E_NUM];
    #pragma unroll
    for (int e = 0; e < E_NUM; ++e) {
      float p = 0.f;
      #pragma unroll
      for (int i = 0; i < 16; ++i) p += xv[i] * Wr[(i*64 + lane)*E_NUM + e];
      #pragma unroll
      for (int off = 32; off >= 1; off >>= 1) p += __shfl_xor(p, off);
      pe[e] = p + br[e];
    }
    float m = pe[0];
    #pragma unroll
    for (int e = 1; e < E_NUM; ++e) m = fmaxf(m, pe[e]);
    float s = 0.f;
    #pragma unroll
    for (int e = 0; e < E_NUM; ++e) { pe[e] = expf(pe[e] - m); s += pe[e]; }
    const float inv = 1.f / s;
    int e1 = 0; float v1 = pe[0];
    #pragma unroll
    for (int e = 1; e < E_NUM; ++e) if (pe[e] > v1) { v1 = pe[e]; e1 = e; }
    int e2 = (e1 == 0) ? 1 : 0; float v2 = pe[e2];
    #pragma unroll
    for (int e = 0; e < E_NUM; ++e) if (e != e1 && pe[e] > v2) { v2 = pe[e]; e2 = e; }
    if (lane == 0) {
      #pragma unroll
      for (int e = 0; e < E_NUM; ++e) probs_out[(size_t)t*E_NUM + e] = pe[e] * inv;
      topi[t*2+0] = e1; topw[t*2+0] = v1 * inv;
      topi[t*2+1] = e2; topw[t*2+1] = v2 * inv;
      atomicAdd(&counts[e1], 1);
      atomicAdd(&counts[e2], 1);
    }
  } else {
    // W1 transpose strip: 8 subtiles of 64x64. 128 strips/expert.
    const int tb = b - T_TOK/4;               // 0..1023
    const int e = tb >> 7;
    const int rem = tb & 127;
    const int c0 = (rem >> 1) * 64;           // 64 c-tiles over F
    const int rg = (rem & 1) * 512;           // 2 r-groups over D
    const size_t eo = (size_t)e * D_DIM * F_DIM;
    const int t = threadIdx.x;
    const int rr = t >> 4, cc = (t & 15) * 4;
    const int kc = (t & 7) * 8, nn0 = t >> 3;
    for (int s = 0; s < 8; ++s) {
      const int r0 = rg + s * 64;
      #pragma unroll
      for (int p = 0; p < 4; ++p) {
        const float4 v = *(const float4*)&W1[eo + (size_t)(r0 + p*16 + rr)*F_DIM + c0 + cc];
        ls[p*16+rr][cc+0]=f2bf(v.x); ls[p*16+rr][cc+1]=f2bf(v.y);
        ls[p*16+rr][cc+2]=f2bf(v.z); ls[p*16+rr][cc+3]=f2bf(v.w);
      }
      __syncthreads();
      #pragma unroll
      for (int p = 0; p < 2; ++p) {
        const int nn = nn0 + p*32;
        ushort8v o;
        #pragma unroll
        for (int j = 0; j < 8; ++j) o[j] = ls[kc + j][nn];
        *(ushort8v*)&W1t[eo + (size_t)(c0 + nn)*D_DIM + r0 + kc] = o;
      }
      __syncthreads();
    }
  }
}

// assign with folded scan: every block recomputes 128-padded bases locally;
// block 0 also writes tile_e. cursor pre-zeroed by memset.
__global__ __launch_bounds__(256) void k_assign(
    const int* __restrict__ counts,
    const int* __restrict__ topi, const float* __restrict__ topw,
    int* __restrict__ cursor,
    int* __restrict__ rows_token, float* __restrict__ rows_w,
    int* __restrict__ pair_of, int* __restrict__ tile_e)
{
  __shared__ int base_s[E_NUM + 1];
  if (threadIdx.x == 0) {
    int base = 0;
    #pragma unroll
    for (int e = 0; e < E_NUM; ++e) {
      base_s[e] = base;
      base += ((counts[e] + 127) >> 7) << 7;
    }
    base_s[E_NUM] = base;
  }
  __syncthreads();
  if (blockIdx.x == 0 && threadIdx.x < N_TILES) {
    const int r0 = threadIdx.x << 7;
    int e = -1;
    #pragma unroll
    for (int k = 0; k < E_NUM; ++k)
      if (r0 >= base_s[k] && r0 < base_s[k+1]) e = k;
    tile_e[threadIdx.x] = e;
  }
  const int t = blockIdx.x * 256 + threadIdx.x;
  if (t < T_TOK) {
    #pragma unroll
    for (int k = 0; k < 2; ++k) {
      const int e = topi[t*2+k];
      const int slot = atomicAdd(&cursor[e], 1);
      const int pid = base_s[e] + slot;
      rows_token[pid] = t;
      rows_w[pid] = topw[t*2+k];
      pair_of[t*2+k] = pid;
    }
  }
}

// transpose + convert (fallback path): per expert, fp32 [R][C] -> bf16 [C][R]
template<int R, int C>
__global__ __launch_bounds__(256) void k_tcvt(const float* __restrict__ in,
                                              unsigned short* __restrict__ out)
{
  const size_t eo = (size_t)blockIdx.z * R * C;
  const int r0 = blockIdx.y * 64, c0 = blockIdx.x * 64;
  __shared__ unsigned short ls[64][66];
  const int t = threadIdx.x;
  const int rr = t >> 4, cc = (t & 15) * 4;
  #pragma unroll
  for (int p = 0; p < 4; ++p) {
    const float4 v = *(const float4*)&in[eo + (size_t)(r0 + p*16 + rr)*C + c0 + cc];
    ls[p*16+rr][cc+0]=f2bf(v.x); ls[p*16+rr][cc+1]=f2bf(v.y);
    ls[p*16+rr][cc+2]=f2bf(v.z); ls[p*16+rr][cc+3]=f2bf(v.w);
  }
  __syncthreads();
  const int kc = (t & 7) * 8, nn0 = t >> 3;
  #pragma unroll
  for (int p = 0; p < 2; ++p) {
    const int nn = nn0 + p*32;
    ushort8v o;
    #pragma unroll
    for (int j = 0; j < 8; ++j) o[j] = ls[kc + j][nn];
    *(ushort8v*)&out[eo + (size_t)(c0 + nn)*R + r0 + kc] = o;
  }
}

// R11 GEMM tile body: BM=BN=128, BK=64, 4 waves (2Mx2N), 2-buffer 64KB LDS.
// Per K-tile: stage(t+1)->buf^1, 16 ds_read, 32 MFMA (setprio), vmcnt(0), bar.
// C[r,n] = sum_k A[r,k]*Bt[n,k].
// EPI 1: relu(acc+bias) -> h.   EPI 2: (acc + (z==0)*bias)*rows_w -> ypart[z].
template<bool GATHER, int NDIM, int KFULL, int EPI>
static __device__ __forceinline__ void gemm_tile(
    const unsigned short* __restrict__ A,
    const unsigned short* __restrict__ Bt,
    const float* __restrict__ bias,
    const int* __restrict__ tile_e,
    const int* __restrict__ rows_token,
    const float* __restrict__ rows_w,
    unsigned short* __restrict__ outp,
    int bx, int by, int z, int nkt, int kch,
    unsigned short (*LB)[256*64])
{
  const int e = tile_e[by];
  if (e < 0) return;
  const int rt = by * 128;
  const int ntc = bx * 128;
  const int koff = z * kch;
  const int tid = threadIdx.x;
  const int lane = tid & 63;
  const int w = tid >> 6;
  const int lr = lane >> 3;
  const int g  = (lane & 7) ^ lr;          // pre-swizzled 16B chunk
  const unsigned short* gp[8];
  unsigned lbase[8];
  if (w < 2) {
    #pragma unroll
    for (int i = 0; i < 8; ++i) {
      const int rl = w*64 + i*8 + lr;
      const int rowidx = GATHER ? rows_token[rt + rl] : (rt + rl);
      gp[i] = A + (size_t)rowidx * KFULL + koff + g*8;
      lbase[i] = (unsigned)((w*64 + i*8) * 64);
    }
  } else {
    const unsigned short* Be = Bt + (size_t)e * NDIM * KFULL;
    #pragma unroll
    for (int i = 0; i < 8; ++i) {
      const int rl = (w-2)*64 + i*8 + lr;
      gp[i] = Be + (size_t)(ntc + rl) * KFULL + koff + g*8;
      lbase[i] = (unsigned)((128*64) + ((w-2)*64 + i*8) * 64);
    }
  }
  const int wr = w >> 1, wc = w & 1;       // 2M x 2N, wave tile 64x64
  const int cl = lane & 15, rgb = lane >> 4;
  const int sz = cl & 7;                   // read-side XOR (row&7 == cl&7)
  f32x4 acc[4][4] = {};

  #define STG8(tt, bb)                                          \
    { const int _ko = (tt) * 64;                                \
      _Pragma("unroll")                                         \
      for (int _i = 0; _i < 8; ++_i)                            \
        gload16(gp[_i] + _ko, &LB[bb][lbase[_i]]); }

  STG8(0, 0)
  asm volatile("s_waitcnt vmcnt(0)" ::: "memory");
  __builtin_amdgcn_s_barrier();

  for (int t = 0; t < nkt; ++t) {
    const int bb = t & 1;
    if (t + 1 < nkt) STG8(t+1, bb^1)       // flies under reads+MFMA
    const unsigned short* Sb = &LB[bb][0];
    short8v a[4][2], b[4][2];
    #pragma unroll
    for (int m = 0; m < 4; ++m) {
      a[m][0] = *(const short8v*)&Sb[(wr*64 + m*16 + cl)*64 + ((0*4+rgb)^sz)*8];
      a[m][1] = *(const short8v*)&Sb[(wr*64 + m*16 + cl)*64 + ((1*4+rgb)^sz)*8];
    }
    #pragma unroll
    for (int n = 0; n < 4; ++n) {
      b[n][0] = *(const short8v*)&Sb[(128*64) + (wc*64 + n*16 + cl)*64 + ((0*4+rgb)^sz)*8];
      b[n][1] = *(const short8v*)&Sb[(128*64) + (wc*64 + n*16 + cl)*64 + ((1*4+rgb)^sz)*8];
    }
    __builtin_amdgcn_s_setprio(1);
    #pragma unroll
    for (int m = 0; m < 4; ++m)
      #pragma unroll
      for (int n = 0; n < 4; ++n) {
        acc[m][n] = __builtin_amdgcn_mfma_f32_16x16x32_bf16(a[m][0], b[n][0], acc[m][n], 0, 0, 0);
        acc[m][n] = __builtin_amdgcn_mfma_f32_16x16x32_bf16(a[m][1], b[n][1], acc[m][n], 0, 0, 0);
      }
    __builtin_amdgcn_s_setprio(0);
    asm volatile("s_waitcnt vmcnt(0)" ::: "memory");   // t+1 landed
    __builtin_amdgcn_s_barrier();
  }
  #undef STG8

  // epilogue: C/D layout col = lane&15, row = (lane>>4)*4 + reg  [m89]
  unsigned short* op = outp;
  if (EPI == 2) op += (size_t)z * CAP_ROWS * NDIM;
  const bool addb = (EPI == 1) || (z == 0);
  const size_t ebias = (size_t)e * NDIM;
  #pragma unroll
  for (int m = 0; m < 4; ++m) {
    const int row = rt + wr*64 + m*16 + rgb*4;
    float4 rw4 = make_float4(0,0,0,0);
    if (EPI == 2) rw4 = *(const float4*)&rows_w[row];
    #pragma unroll
    for (int n = 0; n < 4; ++n) {
      const int col = ntc + wc*64 + n*16 + cl;
      const float bv = addb ? bias[ebias + col] : 0.f;
      #pragma unroll
      for (int r = 0; r < 4; ++r) {
        float v = acc[m][n][r] + bv;
        if (EPI == 1) v = fmaxf(v, 0.f);
        else          v *= ((const float*)&rw4)[r];
        const unsigned short hb = f2bf(v);
        const unsigned short ob = (unsigned short)__shfl_xor((int)(unsigned)hb, 1);
        if ((lane & 1) == 0) {
          const unsigned pk = (unsigned)hb | ((unsigned)ob << 16);
          *(unsigned*)&op[(size_t)(row + r)*NDIM + col] = pk;
        }
      }
    }
  }
}

// standalone GEMM with R11's XCD-bijective B-panel-major swizzle
template<bool GATHER, int NDIM, int KFULL, int EPI>
__global__ __launch_bounds__(256, 2) void k_gemm(
    const unsigned short* __restrict__ A,
    const unsigned short* __restrict__ Bt,
    const float* __restrict__ bias,
    const int* __restrict__ tile_e,
    const int* __restrict__ rows_token,
    const float* __restrict__ rows_w,
    unsigned short* __restrict__ outp,
    int nkt, int kch)
{
  __shared__ __align__(16) unsigned short LB[2][256 * 64];
  const int tot = gridDim.x * gridDim.y;
  int flat = blockIdx.x * gridDim.y + blockIdx.y;
  flat = (flat & 7) * (tot >> 3) + (flat >> 3);
  gemm_tile<GATHER, NDIM, KFULL, EPI>(A, Bt, bias, tile_e, rows_token, rows_w,
                                      outp, flat / gridDim.y, flat % gridDim.y,
                                      blockIdx.z, nkt, kch, LB);
}

// fused launch: blocks [0,2304) = GEMM1 tiles (R11 mapping);
// blocks [2304, 2304+1024) = W2 transpose strips (8x 64x64 subtiles each).
__global__ __launch_bounds__(256, 2) void k_fused1(
    const unsigned short* __restrict__ xbf,
    const unsigned short* __restrict__ W1t,
    const float* __restrict__ b1,
    const int* __restrict__ tile_e,
    const int* __restrict__ rows_token,
    const float* __restrict__ rows_w,
    unsigned short* __restrict__ h,
    const float* __restrict__ W2,
    unsigned short* __restrict__ W2t)
{
  __shared__ __align__(16) unsigned short LB[2][256 * 64];
  constexpr int NG = (F_DIM/128) * N_TILES;   // 2304
  const int b = blockIdx.x;
  if (b < NG) {
    const int x = b & 31;                     // F_DIM/128 = 32
    const int y = b >> 5;
    int flat = x * N_TILES + y;
    flat = (flat & 7) * (NG >> 3) + (flat >> 3);
    gemm_tile<true, F_DIM, D_DIM, 1>(xbf, W1t, b1, tile_e, rows_token, rows_w,
                                     h, flat / N_TILES, flat % N_TILES, 0,
                                     D_DIM/64, D_DIM, LB);
  } else {
    // W2 [E][F][D] fp32 -> W2t [E][D][F] bf16; strip = 8 r-subtiles
    auto ls = (unsigned short (*)[66])(&LB[0][0]);
    const int tb = b - NG;                    // 0..1023
    const int e = tb >> 7;
    const int rem = tb & 127;
    const int c0 = (rem & 15) * 64;
    const int rg = (rem >> 4) * 512;
    const size_t eo = (size_t)e * F_DIM * D_DIM;
    const int t = threadIdx.x;
    const int rr = t >> 4, cc = (t & 15) * 4;
    const int kc = (t & 7) * 8, nn0 = t >> 3;
    for (int s = 0; s < 8; ++s) {
      const int r0 = rg + s * 64;
      #pragma unroll
      for (int p = 0; p < 4; ++p) {
        const float4 v = *(const float4*)&W2[eo + (size_t)(r0 + p*16 + rr)*D_DIM + c0 + cc];
        ls[p*16+rr][cc+0]=f2bf(v.x); ls[p*16+rr][cc+1]=f2bf(v.y);
        ls[p*16+rr][cc+2]=f2bf(v.z); ls[p*16+rr][cc+3]=f2bf(v.w);
      }
      __syncthreads();
      #pragma unroll
      for (int p = 0; p < 2; ++p) {
        const int nn = nn0 + p*32;
        ushort8v o;
        #pragma unroll
        for (int j = 0; j < 8; ++j) o[j] = ls[kc + j][nn];
        *(ushort8v*)&W2t[eo + (size_t)(c0 + nn)*F_DIM + r0 + kc] = o;
      }
      __syncthreads();
    }
  }
}

// out[t] = sum_k sum_s ypart[s][pair_k(t)]  (fixed order -> deterministic)
__global__ __launch_bounds__(256) void k_combine(
    const unsigned short* __restrict__ yp, const int* __restrict__ pair_of,
    float* __restrict__ out, int ksplit)
{
  const int gid = blockIdx.x * 256 + threadIdx.x;   // T*D/8 threads
  const int t = gid >> 7;
  const int c = (gid & 127) * 8;
  float o[8] = {0,0,0,0,0,0,0,0};
  #pragma unroll
  for (int k = 0; k < 2; ++k) {
    const int p = pair_of[t*2+k];
    for (int s = 0; s < ksplit; ++s) {
      const ushort8v v = *(const ushort8v*)&yp[((size_t)s*CAP_ROWS + p)*D_DIM + c];
      #pragma unroll
      for (int j = 0; j < 8; ++j) o[j] += bf2f(v[j]);
    }
  }
  float4 o0; o0.x=o[0]; o0.y=o[1]; o0.z=o[2]; o0.w=o[3];
  float4 o1; o1.x=o[4]; o1.y=o[5]; o1.z=o[6]; o1.w=o[7];
  *(float4*)&out[(size_t)t*D_DIM + c]     = o0;
  *(float4*)&out[(size_t)t*D_DIM + c + 4] = o1;
}

extern "C" void kernel_launch(void* const* d_in, const int* in_sizes, int n_in,
                              void* d_out, int out_size, void* d_ws, size_t ws_size,
                              hipStream_t stream)
{
  const float* x  = (const float*)d_in[0];
  const float* Wr = (const float*)d_in[1];
  const float* br = (const float*)d_in[2];
  const float* W1 = (const float*)d_in[3];
  const float* b1 = (const float*)d_in[4];
  const float* W2 = (const float*)d_in[5];
  const float* b2 = (const float*)d_in[6];
  (void)in_sizes; (void)n_in; (void)out_size;

  float* out   = (float*)d_out;
  float* probs = out + (size_t)T_TOK * D_DIM;

  char* w = (char*)d_ws;
  size_t off = 0;
  // contiguous zero-init region
  int*   counts     = (int*)(w + off); off += 256;
  int*   cursor     = (int*)(w + off); off += 256;
  int*   rows_token = (int*)(w + off); off += (size_t)CAP_ROWS*4;
  float* rows_w     = (float*)(w + off); off += (size_t)CAP_ROWS*4;
  const size_t zbytes = off;
  int*   tile_e     = (int*)(w + off); off += 3072;
  int*   topi       = (int*)(w + off); off += (size_t)T_TOK*2*4;
  float* topw       = (float*)(w + off); off += (size_t)T_TOK*2*4;
  int*   pair_of    = (int*)(w + off); off += (size_t)T_TOK*2*4;
  off = (off + 255) & ~(size_t)255;
  unsigned short* xbf = (unsigned short*)(w + off); off += (size_t)T_TOK*D_DIM*2;
  unsigned short* W1t = (unsigned short*)(w + off); off += (size_t)E_NUM*D_DIM*F_DIM*2;

  const size_t WT = (size_t)E_NUM*D_DIM*F_DIM*2;   // 67.1 MB
  const size_t HB = (size_t)CAP_ROWS*F_DIM*2;      // 75.5 MB
  const size_t YP = (size_t)CAP_ROWS*D_DIM*2;      // 18.9 MB

  // decision tree (deterministic: ws_size fixed per run)
  bool fused; int ksplit;
  if      (ws_size >= off + WT + HB + 4*YP) { fused = true;  ksplit = 4; }
  else if (ws_size >= off + WT + HB + 2*YP) { fused = true;  ksplit = 2; }
  else if (ws_size >= off + HB + 4*YP)      { fused = false; ksplit = 4; }
  else if (ws_size >= off + HB + 2*YP)      { fused = false; ksplit = 2; }
  else                                      { fused = false; ksplit = 1; }

  unsigned short* W2t;
  unsigned short* h;
  if (fused) {
    W2t = (unsigned short*)(w + off); off += WT;
    h   = (unsigned short*)(w + off); off += HB;
  } else {
    W2t = W1t;                                   // sequential reuse
    h   = (unsigned short*)(w + off); off += HB;
  }
  unsigned short* yp = (unsigned short*)(w + off);
  const int kch2 = F_DIM / ksplit;
  const int nkt2 = kch2 / 64;

  hipMemsetAsync(d_ws, 0, zbytes, stream);
  // fused0: router (1024 blocks) + W1 transpose (1024 strips)
  k_fused0<<<T_TOK/4 + 1024, 256, 0, stream>>>(
      x, Wr, br, probs, topi, topw, counts, xbf, W1, W1t);
  k_assign<<<T_TOK / 256, 256, 0, stream>>>(counts, topi, topw, cursor,
                                            rows_token, rows_w, pair_of, tile_e);
  if (fused) {
    // GEMM1 (2304 tiles) + W2 transpose (1024 strips) in ONE launch
    k_fused1<<<(F_DIM/128)*N_TILES + 1024, 256, 0, stream>>>(
        xbf, W1t, b1, tile_e, rows_token, rows_w, h, W2, W2t);
  } else {
    k_gemm<true, F_DIM, D_DIM, 1><<<dim3(F_DIM/128, N_TILES), 256, 0, stream>>>(
        xbf, W1t, b1, tile_e, rows_token, rows_w, h, D_DIM/64, D_DIM);
    k_tcvt<F_DIM, D_DIM><<<dim3(D_DIM/64, F_DIM/64, E_NUM), 256, 0, stream>>>(W2, W2t);
  }
  // GEMM2: K split into ksplit chunks along blockIdx.z
  k_gemm<false, D_DIM, F_DIM, 2><<<dim3(D_DIM/128, N_TILES, ksplit), 256, 0, stream>>>(
      h, W2t, b2, tile_e, rows_token, rows_w, yp, nkt2, kch2);
  k_combine<<<T_TOK * D_DIM / 8 / 256, 256, 0, stream>>>(yp, pair_of, out, ksplit);
}

// Round 19
// 429.797 us; speedup vs baseline: 1.3555x; 1.0217x over previous
//
#include <hip/hip_runtime.h>
#include <hip/hip_bf16.h>

// MoE layer: B=2,S=2048,D=1024,F=4096,E=8,K=2. T=4096 tokens.
// R19: R18 structure with GEMM at BK=32 / 32KB 2-buffer LDS ->
// 4-5 blocks/CU (blocks/CU = the only lever that measured across 12
// variants). Staging/swizzle = R8's proven 4-chunk scheme. All else = R18.

#define T_TOK 4096
#define D_DIM 1024
#define F_DIM 4096
#define E_NUM 8
#define CAP_ROWS 9216          // 8192 + 8*128 padding headroom
#define N_TILES (CAP_ROWS/128) // 72

typedef __attribute__((ext_vector_type(8))) short short8v;
typedef __attribute__((ext_vector_type(8))) unsigned short ushort8v;
typedef __attribute__((ext_vector_type(4))) float f32x4;

static __device__ __forceinline__ unsigned short f2bf(float f){
  union { float f; unsigned u; } v; v.f = f;
  unsigned r = (v.u + 0x7fffu + ((v.u >> 16) & 1u)) >> 16;  // RNE
  return (unsigned short)r;
}
static __device__ __forceinline__ float bf2f(unsigned short s){
  union { unsigned u; float f; } v; v.u = ((unsigned)s) << 16;
  return v.f;
}

static __device__ __forceinline__ void gload16(const void* g, void* l) {
  __builtin_amdgcn_global_load_lds(
      (const __attribute__((address_space(1))) unsigned int*)g,
      (__attribute__((address_space(3))) unsigned int*)l, 16, 0, 0);
}

// fused0: blocks [0,1024) = router (one wave per token; probs+top2+xbf);
// blocks [1024,2048) = W1 [E][D][F] fp32 -> W1t [E][F][D] bf16 strips.
__global__ __launch_bounds__(256) void k_fused0(
    const float* __restrict__ x, const float* __restrict__ Wr,
    const float* __restrict__ br, float* __restrict__ probs_out,
    int* __restrict__ topi, float* __restrict__ topw, int* __restrict__ counts,
    unsigned short* __restrict__ xbf,
    const float* __restrict__ W1, unsigned short* __restrict__ W1t)
{
  __shared__ unsigned short ls[64][66];
  const int b = blockIdx.x;
  if (b < T_TOK/4) {
    const int lane = threadIdx.x & 63;
    const int t = b * 4 + (threadIdx.x >> 6);
    float xv[16];
    #pragma unroll
    for (int i = 0; i < 16; ++i) xv[i] = x[(size_t)t*D_DIM + i*64 + lane];
    #pragma unroll
    for (int i = 0; i < 16; ++i) xbf[(size_t)t*D_DIM + i*64 + lane] = f2bf(xv[i]);
    float pe[E_NUM];
    #pragma unroll
    for (int e = 0; e < E_NUM; ++e) {
      float p = 0.f;
      #pragma unroll
      for (int i = 0; i < 16; ++i) p += xv[i] * Wr[(i*64 + lane)*E_NUM + e];
      #pragma unroll
      for (int off = 32; off >= 1; off >>= 1) p += __shfl_xor(p, off);
      pe[e] = p + br[e];
    }
    float m = pe[0];
    #pragma unroll
    for (int e = 1; e < E_NUM; ++e) m = fmaxf(m, pe[e]);
    float s = 0.f;
    #pragma unroll
    for (int e = 0; e < E_NUM; ++e) { pe[e] = expf(pe[e] - m); s += pe[e]; }
    const float inv = 1.f / s;
    int e1 = 0; float v1 = pe[0];
    #pragma unroll
    for (int e = 1; e < E_NUM; ++e) if (pe[e] > v1) { v1 = pe[e]; e1 = e; }
    int e2 = (e1 == 0) ? 1 : 0; float v2 = pe[e2];
    #pragma unroll
    for (int e = 0; e < E_NUM; ++e) if (e != e1 && pe[e] > v2) { v2 = pe[e]; e2 = e; }
    if (lane == 0) {
      #pragma unroll
      for (int e = 0; e < E_NUM; ++e) probs_out[(size_t)t*E_NUM + e] = pe[e] * inv;
      topi[t*2+0] = e1; topw[t*2+0] = v1 * inv;
      topi[t*2+1] = e2; topw[t*2+1] = v2 * inv;
      atomicAdd(&counts[e1], 1);
      atomicAdd(&counts[e2], 1);
    }
  } else {
    // W1 transpose strip: 8 subtiles of 64x64. 128 strips/expert.
    const int tb = b - T_TOK/4;               // 0..1023
    const int e = tb >> 7;
    const int rem = tb & 127;
    const int c0 = (rem >> 1) * 64;           // 64 c-tiles over F
    const int rg = (rem & 1) * 512;           // 2 r-groups over D
    const size_t eo = (size_t)e * D_DIM * F_DIM;
    const int t = threadIdx.x;
    const int rr = t >> 4, cc = (t & 15) * 4;
    const int kc = (t & 7) * 8, nn0 = t >> 3;
    for (int s = 0; s < 8; ++s) {
      const int r0 = rg + s * 64;
      #pragma unroll
      for (int p = 0; p < 4; ++p) {
        const float4 v = *(const float4*)&W1[eo + (size_t)(r0 + p*16 + rr)*F_DIM + c0 + cc];
        ls[p*16+rr][cc+0]=f2bf(v.x); ls[p*16+rr][cc+1]=f2bf(v.y);
        ls[p*16+rr][cc+2]=f2bf(v.z); ls[p*16+rr][cc+3]=f2bf(v.w);
      }
      __syncthreads();
      #pragma unroll
      for (int p = 0; p < 2; ++p) {
        const int nn = nn0 + p*32;
        ushort8v o;
        #pragma unroll
        for (int j = 0; j < 8; ++j) o[j] = ls[kc + j][nn];
        *(ushort8v*)&W1t[eo + (size_t)(c0 + nn)*D_DIM + r0 + kc] = o;
      }
      __syncthreads();
    }
  }
}

// assign with folded scan: every block recomputes 128-padded bases locally;
// block 0 also writes tile_e. cursor pre-zeroed by memset.
__global__ __launch_bounds__(256) void k_assign(
    const int* __restrict__ counts,
    const int* __restrict__ topi, const float* __restrict__ topw,
    int* __restrict__ cursor,
    int* __restrict__ rows_token, float* __restrict__ rows_w,
    int* __restrict__ pair_of, int* __restrict__ tile_e)
{
  __shared__ int base_s[E_NUM + 1];
  if (threadIdx.x == 0) {
    int base = 0;
    #pragma unroll
    for (int e = 0; e < E_NUM; ++e) {
      base_s[e] = base;
      base += ((counts[e] + 127) >> 7) << 7;
    }
    base_s[E_NUM] = base;
  }
  __syncthreads();
  if (blockIdx.x == 0 && threadIdx.x < N_TILES) {
    const int r0 = threadIdx.x << 7;
    int e = -1;
    #pragma unroll
    for (int k = 0; k < E_NUM; ++k)
      if (r0 >= base_s[k] && r0 < base_s[k+1]) e = k;
    tile_e[threadIdx.x] = e;
  }
  const int t = blockIdx.x * 256 + threadIdx.x;
  if (t < T_TOK) {
    #pragma unroll
    for (int k = 0; k < 2; ++k) {
      const int e = topi[t*2+k];
      const int slot = atomicAdd(&cursor[e], 1);
      const int pid = base_s[e] + slot;
      rows_token[pid] = t;
      rows_w[pid] = topw[t*2+k];
      pair_of[t*2+k] = pid;
    }
  }
}

// transpose + convert (fallback path): per expert, fp32 [R][C] -> bf16 [C][R]
template<int R, int C>
__global__ __launch_bounds__(256) void k_tcvt(const float* __restrict__ in,
                                              unsigned short* __restrict__ out)
{
  const size_t eo = (size_t)blockIdx.z * R * C;
  const int r0 = blockIdx.y * 64, c0 = blockIdx.x * 64;
  __shared__ unsigned short ls[64][66];
  const int t = threadIdx.x;
  const int rr = t >> 4, cc = (t & 15) * 4;
  #pragma unroll
  for (int p = 0; p < 4; ++p) {
    const float4 v = *(const float4*)&in[eo + (size_t)(r0 + p*16 + rr)*C + c0 + cc];
    ls[p*16+rr][cc+0]=f2bf(v.x); ls[p*16+rr][cc+1]=f2bf(v.y);
    ls[p*16+rr][cc+2]=f2bf(v.z); ls[p*16+rr][cc+3]=f2bf(v.w);
  }
  __syncthreads();
  const int kc = (t & 7) * 8, nn0 = t >> 3;
  #pragma unroll
  for (int p = 0; p < 2; ++p) {
    const int nn = nn0 + p*32;
    ushort8v o;
    #pragma unroll
    for (int j = 0; j < 8; ++j) o[j] = ls[kc + j][nn];
    *(ushort8v*)&out[eo + (size_t)(c0 + nn)*R + r0 + kc] = o;
  }
}

// GEMM tile body: BM=BN=128, BK=32, 4 waves (2Mx2N), 2-buffer 32KB LDS
// (-> 4-5 blocks/CU). Per K-tile: stage(t+1)->buf^1 (4 calls/wave),
// 8 ds_read, 16 MFMA (setprio), vmcnt(0), barrier. 2-bit XOR swizzle (R8).
// EPI 1: relu(acc+bias) -> h.   EPI 2: (acc + (z==0)*bias)*rows_w -> ypart[z].
template<bool GATHER, int NDIM, int KFULL, int EPI>
static __device__ __forceinline__ void gemm_tile(
    const unsigned short* __restrict__ A,
    const unsigned short* __restrict__ Bt,
    const float* __restrict__ bias,
    const int* __restrict__ tile_e,
    const int* __restrict__ rows_token,
    const float* __restrict__ rows_w,
    unsigned short* __restrict__ outp,
    int bx, int by, int z, int nkt, int kch,
    unsigned short (*LB)[256*32])
{
  const int e = tile_e[by];
  if (e < 0) return;
  const int rt = by * 128;
  const int ntc = bx * 128;
  const int koff = z * kch;
  const int tid = threadIdx.x;
  const int lane = tid & 63;
  const int w = tid >> 6;
  // staging: call = 16 rows x 64B; lane -> row=lane>>2, chunk g=(lane&3)^(row&3)
  const int lr = lane >> 2;
  const int g  = (lane & 3) ^ (lr & 3);
  const unsigned short* gp[4];
  unsigned lbase[4];
  if (w < 2) {
    #pragma unroll
    for (int i = 0; i < 4; ++i) {
      const int rl = w*64 + i*16 + lr;
      const int rowidx = GATHER ? rows_token[rt + rl] : (rt + rl);
      gp[i] = A + (size_t)rowidx * KFULL + koff + g*8;
      lbase[i] = (unsigned)((w*64 + i*16) * 32);
    }
  } else {
    const unsigned short* Be = Bt + (size_t)e * NDIM * KFULL;
    #pragma unroll
    for (int i = 0; i < 4; ++i) {
      const int rl = (w-2)*64 + i*16 + lr;
      gp[i] = Be + (size_t)(ntc + rl) * KFULL + koff + g*8;
      lbase[i] = (unsigned)((128*32) + ((w-2)*64 + i*16) * 32);
    }
  }
  const int wr = w >> 1, wc = w & 1;       // 2M x 2N, wave tile 64x64
  const int cl = lane & 15, rgb = lane >> 4;
  const int ch = (rgb ^ (cl & 3)) * 8;     // read-side XOR (row&3 == cl&3)
  f32x4 acc[4][4] = {};

  #define STG4(tt, bb)                                          \
    { const int _ko = (tt) * 32;                                \
      _Pragma("unroll")                                         \
      for (int _i = 0; _i < 4; ++_i)                            \
        gload16(gp[_i] + _ko, &LB[bb][lbase[_i]]); }

  STG4(0, 0)
  asm volatile("s_waitcnt vmcnt(0)" ::: "memory");
  __builtin_amdgcn_s_barrier();

  for (int t = 0; t < nkt; ++t) {
    const int bb = t & 1;
    if (t + 1 < nkt) STG4(t+1, bb^1)       // flies under reads+MFMA
    const unsigned short* Sb = &LB[bb][0];
    short8v a[4], b[4];
    #pragma unroll
    for (int m = 0; m < 4; ++m)
      a[m] = *(const short8v*)&Sb[(wr*64 + m*16 + cl)*32 + ch];
    #pragma unroll
    for (int n = 0; n < 4; ++n)
      b[n] = *(const short8v*)&Sb[(128*32) + (wc*64 + n*16 + cl)*32 + ch];
    __builtin_amdgcn_s_setprio(1);
    #pragma unroll
    for (int m = 0; m < 4; ++m)
      #pragma unroll
      for (int n = 0; n < 4; ++n)
        acc[m][n] = __builtin_amdgcn_mfma_f32_16x16x32_bf16(a[m], b[n], acc[m][n], 0, 0, 0);
    __builtin_amdgcn_s_setprio(0);
    asm volatile("s_waitcnt vmcnt(0)" ::: "memory");   // t+1 landed
    __builtin_amdgcn_s_barrier();
  }
  #undef STG4

  // epilogue: C/D layout col = lane&15, row = (lane>>4)*4 + reg  [m89]
  unsigned short* op = outp;
  if (EPI == 2) op += (size_t)z * CAP_ROWS * NDIM;
  const bool addb = (EPI == 1) || (z == 0);
  const size_t ebias = (size_t)e * NDIM;
  #pragma unroll
  for (int m = 0; m < 4; ++m) {
    const int row = rt + wr*64 + m*16 + rgb*4;
    float4 rw4 = make_float4(0,0,0,0);
    if (EPI == 2) rw4 = *(const float4*)&rows_w[row];
    #pragma unroll
    for (int n = 0; n < 4; ++n) {
      const int col = ntc + wc*64 + n*16 + cl;
      const float bv = addb ? bias[ebias + col] : 0.f;
      #pragma unroll
      for (int r = 0; r < 4; ++r) {
        float v = acc[m][n][r] + bv;
        if (EPI == 1) v = fmaxf(v, 0.f);
        else          v *= ((const float*)&rw4)[r];
        const unsigned short hb = f2bf(v);
        const unsigned short ob = (unsigned short)__shfl_xor((int)(unsigned)hb, 1);
        if ((lane & 1) == 0) {
          const unsigned pk = (unsigned)hb | ((unsigned)ob << 16);
          *(unsigned*)&op[(size_t)(row + r)*NDIM + col] = pk;
        }
      }
    }
  }
}

// standalone GEMM with R11's XCD-bijective B-panel-major swizzle
template<bool GATHER, int NDIM, int KFULL, int EPI>
__global__ __launch_bounds__(256, 4) void k_gemm(
    const unsigned short* __restrict__ A,
    const unsigned short* __restrict__ Bt,
    const float* __restrict__ bias,
    const int* __restrict__ tile_e,
    const int* __restrict__ rows_token,
    const float* __restrict__ rows_w,
    unsigned short* __restrict__ outp,
    int nkt, int kch)
{
  __shared__ __align__(16) unsigned short LB[2][256 * 32];
  const int tot = gridDim.x * gridDim.y;
  int flat = blockIdx.x * gridDim.y + blockIdx.y;
  flat = (flat & 7) * (tot >> 3) + (flat >> 3);
  gemm_tile<GATHER, NDIM, KFULL, EPI>(A, Bt, bias, tile_e, rows_token, rows_w,
                                      outp, flat / gridDim.y, flat % gridDim.y,
                                      blockIdx.z, nkt, kch, LB);
}

// fused launch: blocks [0,2304) = GEMM1 tiles (R11 mapping);
// blocks [2304, 2304+1024) = W2 transpose strips (8x 64x64 subtiles each).
__global__ __launch_bounds__(256, 4) void k_fused1(
    const unsigned short* __restrict__ xbf,
    const unsigned short* __restrict__ W1t,
    const float* __restrict__ b1,
    const int* __restrict__ tile_e,
    const int* __restrict__ rows_token,
    const float* __restrict__ rows_w,
    unsigned short* __restrict__ h,
    const float* __restrict__ W2,
    unsigned short* __restrict__ W2t)
{
  __shared__ __align__(16) unsigned short LB[2][256 * 32];
  constexpr int NG = (F_DIM/128) * N_TILES;   // 2304
  const int b = blockIdx.x;
  if (b < NG) {
    const int x = b & 31;                     // F_DIM/128 = 32
    const int y = b >> 5;
    int flat = x * N_TILES + y;
    flat = (flat & 7) * (NG >> 3) + (flat >> 3);
    gemm_tile<true, F_DIM, D_DIM, 1>(xbf, W1t, b1, tile_e, rows_token, rows_w,
                                     h, flat / N_TILES, flat % N_TILES, 0,
                                     D_DIM/32, D_DIM, LB);
  } else {
    // W2 [E][F][D] fp32 -> W2t [E][D][F] bf16; strip = 8 r-subtiles
    auto ls = (unsigned short (*)[66])(&LB[0][0]);
    const int tb = b - NG;                    // 0..1023
    const int e = tb >> 7;
    const int rem = tb & 127;
    const int c0 = (rem & 15) * 64;
    const int rg = (rem >> 4) * 512;
    const size_t eo = (size_t)e * F_DIM * D_DIM;
    const int t = threadIdx.x;
    const int rr = t >> 4, cc = (t & 15) * 4;
    const int kc = (t & 7) * 8, nn0 = t >> 3;
    for (int s = 0; s < 8; ++s) {
      const int r0 = rg + s * 64;
      #pragma unroll
      for (int p = 0; p < 4; ++p) {
        const float4 v = *(const float4*)&W2[eo + (size_t)(r0 + p*16 + rr)*D_DIM + c0 + cc];
        ls[p*16+rr][cc+0]=f2bf(v.x); ls[p*16+rr][cc+1]=f2bf(v.y);
        ls[p*16+rr][cc+2]=f2bf(v.z); ls[p*16+rr][cc+3]=f2bf(v.w);
      }
      __syncthreads();
      #pragma unroll
      for (int p = 0; p < 2; ++p) {
        const int nn = nn0 + p*32;
        ushort8v o;
        #pragma unroll
        for (int j = 0; j < 8; ++j) o[j] = ls[kc + j][nn];
        *(ushort8v*)&W2t[eo + (size_t)(c0 + nn)*F_DIM + r0 + kc] = o;
      }
      __syncthreads();
    }
  }
}

// out[t] = sum_k sum_s ypart[s][pair_k(t)]  (fixed order -> deterministic)
__global__ __launch_bounds__(256) void k_combine(
    const unsigned short* __restrict__ yp, const int* __restrict__ pair_of,
    float* __restrict__ out, int ksplit)
{
  const int gid = blockIdx.x * 256 + threadIdx.x;   // T*D/8 threads
  const int t = gid >> 7;
  const int c = (gid & 127) * 8;
  float o[8] = {0,0,0,0,0,0,0,0};
  #pragma unroll
  for (int k = 0; k < 2; ++k) {
    const int p = pair_of[t*2+k];
    for (int s = 0; s < ksplit; ++s) {
      const ushort8v v = *(const ushort8v*)&yp[((size_t)s*CAP_ROWS + p)*D_DIM + c];
      #pragma unroll
      for (int j = 0; j < 8; ++j) o[j] += bf2f(v[j]);
    }
  }
  float4 o0; o0.x=o[0]; o0.y=o[1]; o0.z=o[2]; o0.w=o[3];
  float4 o1; o1.x=o[4]; o1.y=o[5]; o1.z=o[6]; o1.w=o[7];
  *(float4*)&out[(size_t)t*D_DIM + c]     = o0;
  *(float4*)&out[(size_t)t*D_DIM + c + 4] = o1;
}

extern "C" void kernel_launch(void* const* d_in, const int* in_sizes, int n_in,
                              void* d_out, int out_size, void* d_ws, size_t ws_size,
                              hipStream_t stream)
{
  const float* x  = (const float*)d_in[0];
  const float* Wr = (const float*)d_in[1];
  const float* br = (const float*)d_in[2];
  const float* W1 = (const float*)d_in[3];
  const float* b1 = (const float*)d_in[4];
  const float* W2 = (const float*)d_in[5];
  const float* b2 = (const float*)d_in[6];
  (void)in_sizes; (void)n_in; (void)out_size;

  float* out   = (float*)d_out;
  float* probs = out + (size_t)T_TOK * D_DIM;

  char* w = (char*)d_ws;
  size_t off = 0;
  // contiguous zero-init region
  int*   counts     = (int*)(w + off); off += 256;
  int*   cursor     = (int*)(w + off); off += 256;
  int*   rows_token = (int*)(w + off); off += (size_t)CAP_ROWS*4;
  float* rows_w     = (float*)(w + off); off += (size_t)CAP_ROWS*4;
  const size_t zbytes = off;
  int*   tile_e     = (int*)(w + off); off += 3072;
  int*   topi       = (int*)(w + off); off += (size_t)T_TOK*2*4;
  float* topw       = (float*)(w + off); off += (size_t)T_TOK*2*4;
  int*   pair_of    = (int*)(w + off); off += (size_t)T_TOK*2*4;
  off = (off + 255) & ~(size_t)255;
  unsigned short* xbf = (unsigned short*)(w + off); off += (size_t)T_TOK*D_DIM*2;
  unsigned short* W1t = (unsigned short*)(w + off); off += (size_t)E_NUM*D_DIM*F_DIM*2;

  const size_t WT = (size_t)E_NUM*D_DIM*F_DIM*2;   // 67.1 MB
  const size_t HB = (size_t)CAP_ROWS*F_DIM*2;      // 75.5 MB
  const size_t YP = (size_t)CAP_ROWS*D_DIM*2;      // 18.9 MB

  // decision tree (deterministic: ws_size fixed per run)
  bool fused; int ksplit;
  if      (ws_size >= off + WT + HB + 4*YP) { fused = true;  ksplit = 4; }
  else if (ws_size >= off + WT + HB + 2*YP) { fused = true;  ksplit = 2; }
  else if (ws_size >= off + HB + 4*YP)      { fused = false; ksplit = 4; }
  else if (ws_size >= off + HB + 2*YP)      { fused = false; ksplit = 2; }
  else                                      { fused = false; ksplit = 1; }

  unsigned short* W2t;
  unsigned short* h;
  if (fused) {
    W2t = (unsigned short*)(w + off); off += WT;
    h   = (unsigned short*)(w + off); off += HB;
  } else {
    W2t = W1t;                                   // sequential reuse
    h   = (unsigned short*)(w + off); off += HB;
  }
  unsigned short* yp = (unsigned short*)(w + off);
  const int kch2 = F_DIM / ksplit;
  const int nkt2 = kch2 / 32;

  hipMemsetAsync(d_ws, 0, zbytes, stream);
  // fused0: router (1024 blocks) + W1 transpose (1024 strips)
  k_fused0<<<T_TOK/4 + 1024, 256, 0, stream>>>(
      x, Wr, br, probs, topi, topw, counts, xbf, W1, W1t);
  k_assign<<<T_TOK / 256, 256, 0, stream>>>(counts, topi, topw, cursor,
                                            rows_token, rows_w, pair_of, tile_e);
  if (fused) {
    // GEMM1 (2304 tiles) + W2 transpose (1024 strips) in ONE launch
    k_fused1<<<(F_DIM/128)*N_TILES + 1024, 256, 0, stream>>>(
        xbf, W1t, b1, tile_e, rows_token, rows_w, h, W2, W2t);
  } else {
    k_gemm<true, F_DIM, D_DIM, 1><<<dim3(F_DIM/128, N_TILES), 256, 0, stream>>>(
        xbf, W1t, b1, tile_e, rows_token, rows_w, h, D_DIM/32, D_DIM);
    k_tcvt<F_DIM, D_DIM><<<dim3(D_DIM/64, F_DIM/64, E_NUM), 256, 0, stream>>>(W2, W2t);
  }
  // GEMM2: K split into ksplit chunks along blockIdx.z
  k_gemm<false, D_DIM, F_DIM, 2><<<dim3(D_DIM/128, N_TILES, ksplit), 256, 0, stream>>>(
      h, W2t, b2, tile_e, rows_token, rows_w, yp, nkt2, kch2);
  k_combine<<<T_TOK * D_DIM / 8 / 256, 256, 0, stream>>>(yp, pair_of, out, ksplit);
}